// Round 10
// baseline (28.762 us; speedup 1.0000x reference)
//
#include <hip/hip_runtime.h>

// Problem constants (from reference)
#define BB 2
#define CC 3
#define HH 112
#define WW 112
#define NN (HH*WW)            // 12544
#define NPAIR (BB*CC)         // 6
#define NCOMBO (NPAIR*2)      // 12 masks == 12 directed combos (combo z uses mask m=z)
#define NBINS 24643           // max squared distance 111^2+111^2
#define HWORDS ((NBINS+1)/2)  // 12322 packed words, 2x16-bit bins each
#define HSTRIDE (HWORDS+16)   // per-mask global slice incl. sentinel pad
#define INF29 (1<<29)
#define RCH 4                 // rows per chunk
#define NCHUNK (HH/RCH)       // 28 chunks per mask -> 336 blocks
#define NTHR 512
#define NQ4 (NN/4)            // 3136 4-voxel groups
#define NFW2 (NN/32)          // 392 flat 32-bit mask words
#define POISON 0xAAAAAAAAu    // harness ws poison (uniform per call: all-poison or all-zero)
#define CSTRIDE 16            // 64B spacing between counters
#define CTR_INTS ((NCOMBO+1)*CSTRIDE)

typedef unsigned long long ull;

// argmax over C=3, strict > (first index wins) == jnp.argmax
__device__ __forceinline__ int predLab3(float a, float b, float d) {
    int lab = 0; float best = a;
    if (b > best) { best = b; lab = 1; }
    if (d > best) lab = 2;
    return lab;
}
// keep returning-atomic results live: vmcnt retires only when the op is
// globally performed, and __syncthreads drains vmcnt for every wave.
__device__ __forceinline__ void sinku(unsigned v) { asm volatile("" :: "v"(v)); }
__device__ __forceinline__ void sinkf(float v)    { asm volatile("" :: "v"(v)); }

__global__ __launch_bounds__(NTHR) void fused_kernel(
        const float* __restrict__ x, const int* __restrict__ yl,
        unsigned* __restrict__ ghist, unsigned* __restrict__ ctrs,
        float* __restrict__ qvalg, float* __restrict__ out) {
    __shared__ unsigned flatU[NFW2];     // mask bits, flat voxel order
    __shared__ unsigned colQ[4][WW];     // column bits, 32-row quarters
    __shared__ int G[RCH][WW];           // vertical min-sq-dist, this chunk's rows
    __shared__ unsigned hist[HWORDS];    // block hist, later staged global hist
    __shared__ int wsum[NTHR/64];
    __shared__ float vlh[2];
    __shared__ int lastFlag, gLastFlag;
    __shared__ unsigned pbase;
    __shared__ float rq[NCOMBO];

    const int tid = threadIdx.x;
    const int m     = blockIdx.x / NCHUNK;   // mask / combo 0..11
    const int chunk = blockIdx.x % NCHUNK;   // row-chunk 0..27
    const int r0 = chunk * RCH;
    const int pair = m >> 1, src = m & 1;    // mask side: 0 = gt, 1 = pred
    const int b = pair / CC, c = pair % CC;
    const float* xb = x + (size_t)b * CC * NN;
    const int*   yb = yl + b * NN;
    unsigned* ghm = ghist + m * HSTRIDE;
    unsigned* ctr = ctrs + m * CSTRIDE;
    unsigned* done = ctrs + NCOMBO * CSTRIDE;

    // ---- phase 0: zero LDS bitset + histogram ----
    for (int i = tid; i < NFW2; i += NTHR) flatU[i] = 0u;
    for (int i = tid; i < HWORDS; i += NTHR) hist[i] = 0u;
    __syncthreads();

    // ---- build mask bitset, 4 voxels/thread via vector loads ----
    #pragma unroll
    for (int k = 0; k < (NQ4 + NTHR - 1) / NTHR; k++) {   // 7 iters
        int t4 = k * NTHR + tid;
        if (t4 < NQ4) {
            int v4 = t4 * 4;
            unsigned nib;
            if (src) {
                const float4 a  = *(const float4*)(xb + v4);
                const float4 b4 = *(const float4*)(xb + NN + v4);
                const float4 d4 = *(const float4*)(xb + 2 * NN + v4);
                nib  = (unsigned)(predLab3(a.x, b4.x, d4.x) == c);
                nib |= (unsigned)(predLab3(a.y, b4.y, d4.y) == c) << 1;
                nib |= (unsigned)(predLab3(a.z, b4.z, d4.z) == c) << 2;
                nib |= (unsigned)(predLab3(a.w, b4.w, d4.w) == c) << 3;
            } else {
                const int4 yv = *(const int4*)(yb + v4);
                nib  = (unsigned)(yv.x == c) | ((unsigned)(yv.y == c) << 1)
                     | ((unsigned)(yv.z == c) << 2) | ((unsigned)(yv.w == c) << 3);
            }
            if (nib) atomicOr(&flatU[t4 >> 3], nib << ((t4 & 7) << 2));
        }
    }
    __syncthreads();

    // ---- bit-transpose: flat -> per-column bits, 32-row quarters ----
    if (tid < 4 * WW) {
        int xcolT = tid % WW, q = tid / WW;
        int jmax = (q == 3) ? (HH - 96) : 32;     // 16 or 32 rows
        unsigned acc = 0;
        int p = (q * 32) * WW + xcolT;
        for (int j = 0; j < jmax; j++) {
            acc |= ((flatU[p >> 5] >> (p & 31)) & 1u) << j;
            p += WW;
        }
        colQ[q][xcolT] = acc;
    }
    __syncthreads();

    const int xcol = tid % WW, rsel = tid / WW;
    const bool act = (tid < RCH * WW);            // 448 active

    // ---- phase A: G[rsel][x] = (min |row-y'| over set y' in column x)^2 ----
    if (act) {
        ull lo64 = colQ[0][xcol] | ((ull)colQ[1][xcol] << 32);
        ull hi64 = colQ[2][xcol] | ((ull)colQ[3][xcol] << 32);
        int r = r0 + rsel;
        ull mleLo, mleHi, mgeLo, mgeHi;
        if (r < 64) {                  // (2ull<<63) wraps to 0 -> ~0 mask correctly
            mleLo = (2ull << r) - 1;  mleHi = 0;
            mgeLo = ~((1ull << r) - 1); mgeHi = ~0ull;
        } else {
            int rr = r - 64;           // rr <= 47
            mleLo = ~0ull; mleHi = (2ull << rr) - 1;
            mgeLo = 0;     mgeHi = ~((1ull << rr) - 1);
        }
        ull sL = lo64 & mleLo, sH = hi64 & mleHi;
        ull tL = lo64 & mgeLo, tH = hi64 & mgeHi;
        int posUp = sH ? (127 - (int)__builtin_clzll(sH))
                       : (sL ? (63 - (int)__builtin_clzll(sL)) : -4000);
        int posDn = tL ? (int)__builtin_ctzll(tL)
                       : (tH ? 64 + (int)__builtin_ctzll(tH) : 8000);
        int d = min(r - posUp, posDn - r);   // empty column -> d ~4000 -> g>NBINS (gated later)
        G[rsel][xcol] = d * d;               // exact integer
    }
    __syncthreads();

    // ---- phase B + hist fill (no barrier between: disjoint LDS arrays) ----
    if (act) {
        int a0 = INF29, a1 = INF29, a2 = INF29, a3 = INF29;   // 4 chains for ILP
        #pragma unroll 4
        for (int xx = 0; xx < WW; xx += 4) {
            int d0 = xcol - xx, d1 = xcol - xx - 1, d2v = xcol - xx - 2, d3 = xcol - xx - 3;
            a0 = min(a0, d0 * d0   + G[rsel][xx]);
            a1 = min(a1, d1 * d1   + G[rsel][xx + 1]);
            a2 = min(a2, d2v * d2v + G[rsel][xx + 2]);
            a3 = min(a3, d3 * d3   + G[rsel][xx + 3]);
        }
        int dreg = min(min(a0, a1), min(a2, a3));
        int v = (r0 + rsel) * WW + xcol;
        int qlab = src ? yb[v] : predLab3(xb[v], xb[NN + v], xb[2 * NN + v]);
        if (qlab == c) {                         // query side = opposite of mask side
            int d2 = min(dreg, NBINS - 1);       // clamp only if target mask empty (gated later)
            atomicAdd(&hist[d2 >> 1], 1u << ((d2 & 1) << 4));
        }
    }
    __syncthreads();

    // ---- merge into global hist: plain adds (poison-safe: halves never carry
    // across 0xAAAA since counts <= 12544 < 0x5556; reversed at stage time) ----
    for (int i = tid; i < HWORDS; i += NTHR) {
        unsigned w = hist[i];
        if (w) sinku(atomicAdd(&ghm[i], w));
    }
    __syncthreads();                             // vmcnt(0) drain: merges performed

    // ---- per-mask last-arriver finalizes (no fences, no spinning) ----
    if (tid == 0) {
        unsigned prev = atomicAdd(ctr, 1u);
        if (prev >= POISON) prev -= POISON;      // first-call poison base
        lastFlag = (prev == NCHUNK - 1);
    }
    __syncthreads();
    if (!lastFlag) return;
    if (tid == 0) atomicExch(ctr, 0u);           // re-arm for next call

    // ---- leader: detect first-call via sentinel (bins 6,7-style untouched word) ----
    if (tid == 0) pbase = (atomicExch(&ghm[HWORDS], 0u) == POISON) ? POISON : 0u;
    __syncthreads();
    // stage + self-clean; subtract poison base per word (no borrow possible)
    for (int i = tid; i < HWORDS; i += NTHR)
        hist[i] = atomicExch(&ghm[i], 0u) - pbase;
    __syncthreads();

    // ---- exact linear-interp 95th quantile (bit-identical to reference) ----
    const int CHUNKB = (NBINS + NTHR - 1) / NTHR;   // 49 bins/thread
    int lo = tid * CHUNKB, hiE = min(lo + CHUNKB, NBINS);
    int s = 0;
    for (int i = lo; i < hiE; i++) s += (hist[i >> 1] >> ((i & 1) << 4)) & 0xffff;

    // wave-shuffle inclusive scan (3 barriers total)
    const int lane = tid & 63, wid = tid >> 6;      // 8 waves
    int incl = s;
    #pragma unroll
    for (int o = 1; o < 64; o <<= 1) {
        int t2 = __shfl_up(incl, o, 64);
        if (lane >= o) incl += t2;
    }
    if (lane == 63) wsum[wid] = incl;
    __syncthreads();
    if (wid == 0) {
        int vv = (lane < NTHR / 64) ? wsum[lane] : 0;
        #pragma unroll
        for (int o = 1; o < NTHR / 64; o <<= 1) {
            int t2 = __shfl_up(vv, o, 64);
            if (lane >= o) vv += t2;
        }
        if (lane < NTHR / 64) wsum[lane] = vv;      // inclusive wave sums
    }
    __syncthreads();
    incl += (wid > 0) ? wsum[wid - 1] : 0;
    int excl = incl - s;
    int n = wsum[NTHR / 64 - 1];                    // query-point count for this combo

    float qv = 0.f;
    if (n > 0) {
        float pos  = 0.95f * (float)(n - 1);
        int   klo  = (int)floorf(pos);
        int   khi  = (int)ceilf(pos);
        float frac = pos - (float)klo;
        #pragma unroll
        for (int which = 0; which < 2; which++) {   // both ranks, one barrier after
            int r = which ? khi : klo;
            if (r >= excl && r < incl) {            // rank falls in my chunk
                int cacc = excl;
                for (int i = lo; i < hiE; i++) {
                    cacc += (hist[i >> 1] >> ((i & 1) << 4)) & 0xffff;
                    if (cacc > r) { vlh[which] = sqrtf((float)i); break; }
                }
            }
        }
        __syncthreads();
        qv = vlh[0] * (1.f - frac) + vlh[1] * frac;
    }

    // ---- publish (qv<0 encodes empty) + global last-of-12 finalize ----
    if (tid == 0) sinkf(atomicExch(&qvalg[m], (n > 0) ? qv : -1.0f));
    __syncthreads();                                // drains tid0's publish
    if (tid == 0) {
        unsigned prev = atomicAdd(done, 1u);
        if (prev >= POISON) prev -= POISON;
        gLastFlag = (prev == NCOMBO - 1);
    }
    __syncthreads();
    if (!gLastFlag) return;
    if (tid == 0) atomicExch(done, 0u);             // re-arm

    if (tid < NCOMBO) rq[tid] = atomicAdd(&qvalg[tid], 0.f);  // coherent reads
    __syncthreads();
    if (tid == 0) {
        float ssum = 0.f;
        for (int p = 0; p < NPAIR; p++) {
            float a = rq[2 * p], b2 = rq[2 * p + 1];
            float hd = (a >= 0.f && b2 >= 0.f) ? fmaxf(a, b2) : 0.f;  // empty set -> 0
            ssum += hd;
        }
        out[0] = ssum / (float)NPAIR;
    }
}

// ---------------------------------------------------------------------------
extern "C" void kernel_launch(void* const* d_in, const int* in_sizes, int n_in,
                              void* d_out, int out_size, void* d_ws, size_t ws_size,
                              hipStream_t stream) {
    const float* x = (const float*)d_in[0];
    const int*   y = (const int*)d_in[1];
    float* out = (float*)d_out;

    // Workspace layout (4B units). No memset node: kernel is poison-robust
    // (uniform-state argument + sentinel) and self-cleaning (leader Exch-zeros).
    unsigned* ws    = (unsigned*)d_ws;
    unsigned* ctrs  = ws;                               // CTR_INTS (arrival counters)
    unsigned* ghist = ctrs + CTR_INTS;                  // NCOMBO*HSTRIDE (hists + sentinels)
    float*    qvalg = (float*)(ghist + NCOMBO*HSTRIDE); // NCOMBO (Exch'd before every read)
    // total ~= 0.6 MB

    fused_kernel<<<NCOMBO * NCHUNK, NTHR, 0, stream>>>(x, y, ghist, ctrs, qvalg, out);
}

// Round 11
// 21.415 us; speedup vs baseline: 1.3431x; 1.3431x over previous
//
#include <hip/hip_runtime.h>

// Problem constants (from reference)
#define BB 2
#define CC 3
#define HH 112
#define WW 112
#define NN (HH*WW)            // 12544
#define NPAIR (BB*CC)         // 6
#define NCOMBO (NPAIR*2)      // 12 masks == 12 directed combos (combo z uses mask m=z)
#define NBINS 24643           // max squared distance 111^2+111^2
#define HWORDS ((NBINS+1)/2)  // 12322 packed words, 2x16-bit bins each
#define INF29 (1<<29)
#define RCH 8                 // rows per chunk
#define NCHUNK (HH/RCH)       // 14 chunks per mask -> 168 blocks
#define NTHR 1024
#define NQ4 (NN/4)            // 3136 4-voxel groups
#define NFW2 (NN/32)          // 392 flat 32-bit mask words
#define NOQ 0xFFFFFFFFu       // "not a query voxel" marker (can't collide with d2<=NBINS-1)
#define POISON 0xAAAAAAAAu    // harness ws poison (uniform: all-poison first call, else prior state)
#define CSTRIDE 16            // 64B spacing between counters
#define CTR_INTS ((NCOMBO+1)*CSTRIDE)

typedef unsigned long long ull;

// argmax over C=3, strict > (first index wins) == jnp.argmax
__device__ __forceinline__ int predLab3(float a, float b, float d) {
    int lab = 0; float best = a;
    if (b > best) { best = b; lab = 1; }
    if (d > best) lab = 2;
    return lab;
}
// keep returning-atomic results live: vmcnt retires only when the op is
// globally performed, and __syncthreads drains vmcnt for every wave.
__device__ __forceinline__ void sinku(unsigned v) { asm volatile("" :: "v"(v)); }
__device__ __forceinline__ void sinkf(float v)    { asm volatile("" :: "v"(v)); }

// Compute scratch and the leader histogram never coexist -> union, ~50KB LDS.
union Smem {
    struct {
        unsigned flatU[NFW2];      // mask bits, flat voxel order
        unsigned colQ[4][WW];      // column bits, 32-row quarters
        int G[RCH][WW];            // vertical min-sq-dist, this chunk's rows
    } ab;
    unsigned hist[HWORDS];         // leader: packed 2x16-bit bins
};

__global__ __launch_bounds__(NTHR) void fused_kernel(
        const float* __restrict__ x, const int* __restrict__ yl,
        unsigned* __restrict__ d2g, unsigned* __restrict__ ctrs,
        float* __restrict__ qvalg, float* __restrict__ out) {
    __shared__ Smem sm;
    __shared__ int wsum[NTHR/64];
    __shared__ float vlh[2];
    __shared__ int lastFlag, gLastFlag;
    __shared__ float rq[NCOMBO];

    const int tid = threadIdx.x;
    const int m     = blockIdx.x / NCHUNK;   // mask / combo 0..11
    const int chunk = blockIdx.x % NCHUNK;   // row-chunk 0..13
    const int r0 = chunk * RCH;
    const int pair = m >> 1, src = m & 1;    // mask side: 0 = gt, 1 = pred
    const int b = pair / CC, c = pair % CC;
    const float* xb = x + (size_t)b * CC * NN;
    const int*   yb = yl + b * NN;
    unsigned* d2m  = d2g + m * NN;
    unsigned* ctr  = ctrs + m * CSTRIDE;
    unsigned* done = ctrs + NCOMBO * CSTRIDE;

    // ---- zero LDS bitset ----
    for (int i = tid; i < NFW2; i += NTHR) sm.ab.flatU[i] = 0u;
    __syncthreads();

    // ---- build mask bitset, 4 voxels/thread via vector loads ----
    #pragma unroll
    for (int k = 0; k < (NQ4 + NTHR - 1) / NTHR; k++) {   // 4 iters
        int t4 = k * NTHR + tid;
        if (t4 < NQ4) {
            int v4 = t4 * 4;
            unsigned nib;
            if (src) {
                const float4 a  = *(const float4*)(xb + v4);
                const float4 b4 = *(const float4*)(xb + NN + v4);
                const float4 d4 = *(const float4*)(xb + 2 * NN + v4);
                nib  = (unsigned)(predLab3(a.x, b4.x, d4.x) == c);
                nib |= (unsigned)(predLab3(a.y, b4.y, d4.y) == c) << 1;
                nib |= (unsigned)(predLab3(a.z, b4.z, d4.z) == c) << 2;
                nib |= (unsigned)(predLab3(a.w, b4.w, d4.w) == c) << 3;
            } else {
                const int4 yv = *(const int4*)(yb + v4);
                nib  = (unsigned)(yv.x == c) | ((unsigned)(yv.y == c) << 1)
                     | ((unsigned)(yv.z == c) << 2) | ((unsigned)(yv.w == c) << 3);
            }
            if (nib) atomicOr(&sm.ab.flatU[t4 >> 3], nib << ((t4 & 7) << 2));
        }
    }
    __syncthreads();

    // ---- bit-transpose: flat -> per-column bits, 32-row quarters ----
    if (tid < 4 * WW) {
        int xcolT = tid % WW, q = tid / WW;
        int jmax = (q == 3) ? (HH - 96) : 32;     // 16 or 32 rows
        unsigned acc = 0;
        int p = (q * 32) * WW + xcolT;
        for (int j = 0; j < jmax; j++) {
            acc |= ((sm.ab.flatU[p >> 5] >> (p & 31)) & 1u) << j;
            p += WW;
        }
        sm.ab.colQ[q][xcolT] = acc;
    }
    __syncthreads();

    const int xcol = tid % WW, rsel = tid / WW;
    const bool act = (tid < RCH * WW);            // 896 active

    // ---- phase A: G[rsel][x] = (min |row-y'| over set y' in column x)^2 ----
    if (act) {
        ull lo64 = sm.ab.colQ[0][xcol] | ((ull)sm.ab.colQ[1][xcol] << 32);
        ull hi64 = sm.ab.colQ[2][xcol] | ((ull)sm.ab.colQ[3][xcol] << 32);
        int r = r0 + rsel;
        ull mleLo, mleHi, mgeLo, mgeHi;
        if (r < 64) {                  // (2ull<<63) wraps to 0 -> ~0 mask correctly
            mleLo = (2ull << r) - 1;  mleHi = 0;
            mgeLo = ~((1ull << r) - 1); mgeHi = ~0ull;
        } else {
            int rr = r - 64;           // rr <= 47
            mleLo = ~0ull; mleHi = (2ull << rr) - 1;
            mgeLo = 0;     mgeHi = ~((1ull << rr) - 1);
        }
        ull sL = lo64 & mleLo, sH = hi64 & mleHi;
        ull tL = lo64 & mgeLo, tH = hi64 & mgeHi;
        int posUp = sH ? (127 - (int)__builtin_clzll(sH))
                       : (sL ? (63 - (int)__builtin_clzll(sL)) : -4000);
        int posDn = tL ? (int)__builtin_ctzll(tL)
                       : (tH ? 64 + (int)__builtin_ctzll(tH) : 8000);
        int d = min(r - posUp, posDn - r);   // empty column -> d ~4000 -> g>NBINS (gated later)
        sm.ab.G[rsel][xcol] = d * d;         // exact integer
    }
    __syncthreads();

    // ---- phase B + direct d2 write (one returning atomic per voxel) ----
    if (act) {
        int a0 = INF29, a1 = INF29, a2 = INF29, a3 = INF29;   // 4 chains for ILP
        #pragma unroll 4
        for (int xx = 0; xx < WW; xx += 4) {                  // broadcast LDS reads
            int d0 = xcol - xx, d1 = xcol - xx - 1, d2v = xcol - xx - 2, d3 = xcol - xx - 3;
            a0 = min(a0, d0 * d0   + sm.ab.G[rsel][xx]);
            a1 = min(a1, d1 * d1   + sm.ab.G[rsel][xx + 1]);
            a2 = min(a2, d2v * d2v + sm.ab.G[rsel][xx + 2]);
            a3 = min(a3, d3 * d3   + sm.ab.G[rsel][xx + 3]);
        }
        int dreg = min(min(a0, a1), min(a2, a3));
        int v = (r0 + rsel) * WW + xcol;
        int qlab = src ? yb[v] : predLab3(xb[v], xb[NN + v], xb[2 * NN + v]);
        // every mask voxel is owned by exactly one thread -> all NN slots are
        // rewritten each call (poison-free by construction)
        unsigned val = (qlab == c) ? (unsigned)min(dreg, NBINS - 1) : NOQ;
        sinku(atomicExch(&d2m[v], val));
    }
    __syncthreads();                             // vmcnt(0) drain: writes performed

    // ---- per-mask last-arriver finalizes (no fences, no spinning) ----
    if (tid == 0) {
        unsigned prev = atomicAdd(ctr, 1u);
        if (prev >= POISON) prev -= POISON;      // first-call poison base
        lastFlag = (prev == NCHUNK - 1);
    }
    __syncthreads();
    if (!lastFlag) return;
    if (tid == 0) atomicExch(ctr, 0u);           // re-arm for next call

    // ---- leader: build packed histogram from the d2 array (coherent atomic reads) ----
    for (int i = tid; i < HWORDS; i += NTHR) sm.hist[i] = 0u;
    __syncthreads();
    #pragma unroll
    for (int k = 0; k < (NN + NTHR - 1) / NTHR; k++) {   // 13 iters
        int i = k * NTHR + tid;
        if (i < NN) {
            unsigned d2 = atomicAdd(&d2m[i], 0u);        // fresh this call, no poison
            if (d2 != NOQ) atomicAdd(&sm.hist[d2 >> 1], 1u << ((d2 & 1) << 4));
        }
    }
    __syncthreads();

    // ---- exact linear-interp 95th quantile (bit-identical to reference) ----
    const int CHUNKB = (NBINS + NTHR - 1) / NTHR;   // 25 bins/thread
    int lo = tid * CHUNKB, hiE = min(lo + CHUNKB, NBINS);
    int s = 0;
    for (int i = lo; i < hiE; i++) s += (sm.hist[i >> 1] >> ((i & 1) << 4)) & 0xffff;

    // wave-shuffle inclusive scan (2 barriers)
    const int lane = tid & 63, wid = tid >> 6;      // 16 waves
    int incl = s;
    #pragma unroll
    for (int o = 1; o < 64; o <<= 1) {
        int t2 = __shfl_up(incl, o, 64);
        if (lane >= o) incl += t2;
    }
    if (lane == 63) wsum[wid] = incl;
    __syncthreads();
    if (wid == 0) {
        int vv = (lane < NTHR / 64) ? wsum[lane] : 0;
        #pragma unroll
        for (int o = 1; o < NTHR / 64; o <<= 1) {
            int t2 = __shfl_up(vv, o, 64);
            if (lane >= o) vv += t2;
        }
        if (lane < NTHR / 64) wsum[lane] = vv;      // inclusive wave sums
    }
    __syncthreads();
    incl += (wid > 0) ? wsum[wid - 1] : 0;
    int excl = incl - s;
    int n = wsum[NTHR / 64 - 1];                    // query-point count for this combo

    float qv = 0.f;
    if (n > 0) {
        float pos  = 0.95f * (float)(n - 1);
        int   klo  = (int)floorf(pos);
        int   khi  = (int)ceilf(pos);
        float frac = pos - (float)klo;
        #pragma unroll
        for (int which = 0; which < 2; which++) {   // both ranks, one barrier after
            int r = which ? khi : klo;
            if (r >= excl && r < incl) {            // rank falls in my chunk
                int cacc = excl;
                for (int i = lo; i < hiE; i++) {
                    cacc += (sm.hist[i >> 1] >> ((i & 1) << 4)) & 0xffff;
                    if (cacc > r) { vlh[which] = sqrtf((float)i); break; }
                }
            }
        }
        __syncthreads();
        qv = vlh[0] * (1.f - frac) + vlh[1] * frac;
    }

    // ---- publish (qv<0 encodes empty) + global last-of-12 finalize ----
    if (tid == 0) sinkf(atomicExch(&qvalg[m], (n > 0) ? qv : -1.0f));
    __syncthreads();                                // drains tid0's publish
    if (tid == 0) {
        unsigned prev = atomicAdd(done, 1u);
        if (prev >= POISON) prev -= POISON;
        gLastFlag = (prev == NCOMBO - 1);
    }
    __syncthreads();
    if (!gLastFlag) return;
    if (tid == 0) atomicExch(done, 0u);             // re-arm

    if (tid < NCOMBO) rq[tid] = atomicAdd(&qvalg[tid], 0.f);  // coherent reads
    __syncthreads();
    if (tid == 0) {
        float ssum = 0.f;
        for (int p = 0; p < NPAIR; p++) {
            float a = rq[2 * p], b2 = rq[2 * p + 1];
            float hd = (a >= 0.f && b2 >= 0.f) ? fmaxf(a, b2) : 0.f;  // empty set -> 0
            ssum += hd;
        }
        out[0] = ssum / (float)NPAIR;
    }
}

// ---------------------------------------------------------------------------
extern "C" void kernel_launch(void* const* d_in, const int* in_sizes, int n_in,
                              void* d_out, int out_size, void* d_ws, size_t ws_size,
                              hipStream_t stream) {
    const float* x = (const float*)d_in[0];
    const int*   y = (const int*)d_in[1];
    float* out = (float*)d_out;

    // Workspace layout (4B units). No memset node: d2g is fully rewritten every
    // call; counters handle poison arithmetically; qvalg is Exch'd before reads.
    unsigned* ws    = (unsigned*)d_ws;
    unsigned* ctrs  = ws;                             // CTR_INTS (arrival counters)
    unsigned* d2g   = ctrs + CTR_INTS;                // NCOMBO*NN (per-mask d2 / NOQ)
    float*    qvalg = (float*)(d2g + NCOMBO * NN);    // NCOMBO
    // total ~= 0.6 MB

    fused_kernel<<<NCOMBO * NCHUNK, NTHR, 0, stream>>>(x, y, d2g, ctrs, qvalg, out);
}